// Round 2
// baseline (2411.601 us; speedup 1.0000x reference)
//
#include <hip/hip_runtime.h>
#include <stdint.h>

// GNSDE scan: B=1024, T=2048, D=16, U=4, H=128, alpha=0.1
// 64 blocks x 256 threads. Block = one 16-row batch tile. Wave w owns
// h-unit slice [32w,32w+32) for layers 0/1; layer 2 redundant per wave.
// All math transposed: MFMA D[row=n(h-unit)][col=m(batch)].
//   C/D layout (verified): col = lane&15, row = 4*(lane>>4)+r
//   A-frag: A[lane&15][8*(lane>>4)+i]   B-frag: B[8*(lane>>4)+i][lane&15]

typedef __attribute__((ext_vector_type(8))) short short8;
typedef __attribute__((ext_vector_type(4))) float f32x4;

#define MF(a, b, c) __builtin_amdgcn_mfma_f32_16x16x32_bf16((a), (b), (c), 0, 0, 0)

static constexpr int Bsz = 1024, Tsz = 2048, Dsz = 16, Usz = 4, Hsz = 128;
static constexpr int H0S = 40;   // h0 row stride (ushorts): 20 used + pad, 2-way banks
static constexpr int HS  = 136;  // h1t/h2t row stride (ushorts): 128 + 8 pad (16B-mult)

static __device__ __forceinline__ unsigned short f2b(float f) {
  union { float f; unsigned u; } v; v.f = f;
  unsigned r = v.u + 0x7FFFu + ((v.u >> 16) & 1u);   // RNE
  return (unsigned short)(r >> 16);
}
static __device__ __forceinline__ unsigned pk2(float a, float b) {
  return (unsigned)f2b(a) | ((unsigned)f2b(b) << 16);
}
static __device__ __forceinline__ float tanh_fast(float x) {
  // tanh(x) = 1 - 2/(2^(2x*log2e)+1); v_exp handles +-inf saturation
  float e = __builtin_amdgcn_exp2f(x * 2.8853900817779268f);
  return 1.0f - 2.0f * __builtin_amdgcn_rcpf(e + 1.0f);
}

__global__ __launch_bounds__(256, 1)
void gnsde_kernel(const float* __restrict__ carry, const float* __restrict__ x,
                  const float* __restrict__ noise, const float* __restrict__ W0,
                  const float* __restrict__ b0v, const float* __restrict__ W1,
                  const float* __restrict__ b1v, const float* __restrict__ W2,
                  const float* __restrict__ b2v, float* __restrict__ out) {
  __shared__ __align__(16) unsigned short h0[4][16 * H0S];  // per-wave [m][k] bf16
  __shared__ __align__(16) unsigned short h1t[16 * HS];     // [m][n] bf16
  __shared__ __align__(16) unsigned short h2t[16 * HS];

  const int w    = threadIdx.x >> 6;   // wave 0..3
  const int lane = threadIdx.x & 63;
  const int m    = lane & 15;          // batch col within tile / A-row
  const int g    = lane >> 4;          // 0..3
  const int brow = blockIdx.x * 16 + m;

  // ---- weights & biases -> per-wave register fragments (one-time) ----
  short8 w0f[2], w1f[2][4], w2f[4];
  f32x4 b0f[2], b1f[2], b2f;
  #pragma unroll
  for (int tp = 0; tp < 2; ++tp) {
    const int n0 = (2 * w + tp) * 16;
    #pragma unroll
    for (int i = 0; i < 8; ++i) {
      const int k = 8 * g + i;  // K padded 20->32 with zeros
      w0f[tp][i] = (short)f2b(k < (Dsz + Usz) ? W0[k * Hsz + n0 + m] : 0.0f);
    }
    #pragma unroll
    for (int kk = 0; kk < 4; ++kk)
      #pragma unroll
      for (int i = 0; i < 8; ++i)
        w1f[tp][kk][i] = (short)f2b(W1[(32 * kk + 8 * g + i) * Hsz + n0 + m]);
    #pragma unroll
    for (int r = 0; r < 4; ++r) {
      b0f[tp][r] = b0v[n0 + 4 * g + r];
      b1f[tp][r] = b1v[n0 + 4 * g + r];
    }
  }
  #pragma unroll
  for (int kk = 0; kk < 4; ++kk)
    #pragma unroll
    for (int i = 0; i < 8; ++i)
      w2f[kk][i] = (short)f2b(W2[(32 * kk + 8 * g + i) * Dsz + m]);
  #pragma unroll
  for (int r = 0; r < 4; ++r) b2f[r] = b2v[4 * g + r];

  // zero own h0 copy (pad cols 20..39 stay zero forever)
  unsigned short* h0w = h0[w];
  #pragma unroll
  for (int i = 0; i < 10; ++i) h0w[lane + 64 * i] = 0;

  // y state in registers, D-layout: y[r] = y[brow][4g+r]
  f32x4 y = *reinterpret_cast<const f32x4*>(&carry[brow * Dsz + 4 * g]);

  const float* xp = x + (size_t)brow * Tsz * Usz;                 // + t*4
  const float* np = noise + (size_t)brow * Tsz * Dsz + 4 * g;     // + t*16
  const size_t BTD = (size_t)Bsz * Tsz * Dsz;
  float* op = out + (size_t)brow * Tsz * Dsz + 4 * g;

  const int h0_y = m * H0S + 4 * g;   // y write (4 bf16)
  const int h0_x = m * H0S + 16;      // x write (4 bf16)
  const int h0_b = m * H0S + 8 * g;   // B-frag read (8 bf16)
  const int hw_o = m * HS + 32 * w + 4 * g;  // h1t/h2t write (+16 for tile 1)
  const int hr_o = m * HS + 8 * g;           // B-frag read (+32*kk)

  f32x4 xv = *reinterpret_cast<const f32x4*>(xp);
  f32x4 nv = *reinterpret_cast<const f32x4*>(np);
  f32x4 xv2 = xv, nv2 = nv;

  #pragma unroll 1
  for (int t = 0; t < Tsz; ++t) {
    // ---------------- phase A: h1 = tanh([y|x] @ W0 + b0) ----------------
    if (t + 1 < Tsz) {  // prefetch next step's x/noise (hidden under compute)
      xv2 = *reinterpret_cast<const f32x4*>(xp + (size_t)(t + 1) * Usz);
      nv2 = *reinterpret_cast<const f32x4*>(np + (size_t)(t + 1) * Dsz);
    }
    uint2 yw; yw.x = pk2(y[0], y[1]); yw.y = pk2(y[2], y[3]);
    *reinterpret_cast<uint2*>(&h0w[h0_y]) = yw;
    if (g == 0) {
      uint2 xw; xw.x = pk2(xv[0], xv[1]); xw.y = pk2(xv[2], xv[3]);
      *reinterpret_cast<uint2*>(&h0w[h0_x]) = xw;
    }
    short8 bh0 = *reinterpret_cast<const short8*>(&h0w[h0_b]);
    f32x4 a00 = b0f[0], a01 = b0f[1];
    a00 = MF(w0f[0], bh0, a00);
    a01 = MF(w0f[1], bh0, a01);
    uint2 p0, p1;
    p0.x = pk2(tanh_fast(a00[0]), tanh_fast(a00[1]));
    p0.y = pk2(tanh_fast(a00[2]), tanh_fast(a00[3]));
    p1.x = pk2(tanh_fast(a01[0]), tanh_fast(a01[1]));
    p1.y = pk2(tanh_fast(a01[2]), tanh_fast(a01[3]));
    *reinterpret_cast<uint2*>(&h1t[hw_o])      = p0;
    *reinterpret_cast<uint2*>(&h1t[hw_o + 16]) = p1;
    __syncthreads();

    // ---------------- phase B: h2 = tanh(h1 @ W1 + b1) ----------------
    short8 q0 = *reinterpret_cast<const short8*>(&h1t[hr_o]);
    short8 q1 = *reinterpret_cast<const short8*>(&h1t[hr_o + 32]);
    short8 q2 = *reinterpret_cast<const short8*>(&h1t[hr_o + 64]);
    short8 q3 = *reinterpret_cast<const short8*>(&h1t[hr_o + 96]);
    f32x4 a10 = b1f[0], a11 = b1f[1];
    a10 = MF(w1f[0][0], q0, a10);  a11 = MF(w1f[1][0], q0, a11);
    a10 = MF(w1f[0][1], q1, a10);  a11 = MF(w1f[1][1], q1, a11);
    a10 = MF(w1f[0][2], q2, a10);  a11 = MF(w1f[1][2], q2, a11);
    a10 = MF(w1f[0][3], q3, a10);  a11 = MF(w1f[1][3], q3, a11);
    p0.x = pk2(tanh_fast(a10[0]), tanh_fast(a10[1]));
    p0.y = pk2(tanh_fast(a10[2]), tanh_fast(a10[3]));
    p1.x = pk2(tanh_fast(a11[0]), tanh_fast(a11[1]));
    p1.y = pk2(tanh_fast(a11[2]), tanh_fast(a11[3]));
    *reinterpret_cast<uint2*>(&h2t[hw_o])      = p0;
    *reinterpret_cast<uint2*>(&h2t[hw_o + 16]) = p1;
    __syncthreads();

    // ------- phase C: mu_theta = h2 @ W2 + b2 (redundant per wave) -------
    short8 c0 = *reinterpret_cast<const short8*>(&h2t[hr_o]);
    short8 c1 = *reinterpret_cast<const short8*>(&h2t[hr_o + 32]);
    short8 c2 = *reinterpret_cast<const short8*>(&h2t[hr_o + 64]);
    short8 c3 = *reinterpret_cast<const short8*>(&h2t[hr_o + 96]);
    f32x4 mt = b2f;
    mt = MF(w2f[0], c0, mt);
    mt = MF(w2f[1], c1, mt);
    mt = MF(w2f[2], c2, mt);
    mt = MF(w2f[3], c3, mt);
    f32x4 mu, yn;
    #pragma unroll
    for (int r = 0; r < 4; ++r) {
      mu[r] = 0.9f * y[r] + 0.1f * mt[r];
      yn[r] = __builtin_fmaf(0.31622776601683794f, nv[r], mu[r]);
    }
    float* o = op + (size_t)t * Dsz;
    if (w == 0)      *reinterpret_cast<f32x4*>(o)            = yn;  // y_seq
    else if (w == 1) *reinterpret_cast<f32x4*>(o + BTD)      = mt;  // mu_theta
    else if (w == 2) *reinterpret_cast<f32x4*>(o + 2 * BTD)  = mu;  // mu
    y = yn; xv = xv2; nv = nv2;
  }
}

extern "C" void kernel_launch(void* const* d_in, const int* in_sizes, int n_in,
                              void* d_out, int out_size, void* d_ws, size_t ws_size,
                              hipStream_t stream) {
  (void)in_sizes; (void)n_in; (void)out_size; (void)d_ws; (void)ws_size;
  gnsde_kernel<<<dim3(Bsz / 16), dim3(256), 0, stream>>>(
      (const float*)d_in[0], (const float*)d_in[1], (const float*)d_in[2],
      (const float*)d_in[3], (const float*)d_in[4], (const float*)d_in[5],
      (const float*)d_in[6], (const float*)d_in[7], (const float*)d_in[8],
      (float*)d_out);
}